// Round 14
// baseline (532.312 us; speedup 1.0000x reference)
//
#include <hip/hip_runtime.h>
#include <math.h>

#define S 512
#define D 512
#define FFD 1024
#define NB 16
#define NL 5

typedef __attribute__((ext_vector_type(8))) short bf16x8;
typedef __attribute__((ext_vector_type(4))) float f32x4;

// ---------------- bf16 helpers ----------------
__device__ __forceinline__ short f2bf(float f){
  union { float f; unsigned u; } c; c.f = f;
  unsigned r = c.u + 0x7FFFu + ((c.u >> 16) & 1u);   // RNE
  return (short)(r >> 16);
}
__device__ __forceinline__ float bf2f(short s){
  union { unsigned u; float f; } c; c.u = ((unsigned)(unsigned short)s) << 16;
  return c.f;
}

// async global->LDS, 16B per lane; lds ptr must be wave-uniform base
__device__ __forceinline__ void gload16(const void* g, void* l){
  __builtin_amdgcn_global_load_lds(
      (const __attribute__((address_space(1))) void*)g,
      (__attribute__((address_space(3))) void*)l, 16, 0, 0);
}

// counted vmcnt wait (T4): wait until at most N of this wave's loads in flight
template<int N>
__device__ __forceinline__ void waitcnt_vm(){
  if      constexpr (N == 0)  asm volatile("s_waitcnt vmcnt(0)"  ::: "memory");
  else if constexpr (N == 2)  asm volatile("s_waitcnt vmcnt(2)"  ::: "memory");
  else if constexpr (N == 4)  asm volatile("s_waitcnt vmcnt(4)"  ::: "memory");
  else if constexpr (N == 6)  asm volatile("s_waitcnt vmcnt(6)"  ::: "memory");
  else if constexpr (N == 8)  asm volatile("s_waitcnt vmcnt(8)"  ::: "memory");
  else if constexpr (N == 10) asm volatile("s_waitcnt vmcnt(10)" ::: "memory");
  else                        asm volatile("s_waitcnt vmcnt(12)" ::: "memory");
}

// ---------------- reduction helpers ----------------
__device__ __forceinline__ float wsum(float v){
  #pragma unroll
  for (int o = 32; o; o >>= 1) v += __shfl_down(v, o, 64);
  return v;
}

// ---------------- fused setup: wtrans | wrel | bcat | embed ----------------
// block-id ranges: [0,2560) wtrans, [2560,3200) wrel, [3200,3233) bcat,
//                  [3233,19617) embed. All branches write disjoint buffers.
__global__ __launch_bounds__(256) void setup_k(
    const int* __restrict__ x, const float* __restrict__ tok,
    const float* __restrict__ rel,
    const float* __restrict__ Wq, const float* __restrict__ Wk,
    const float* __restrict__ Wv, const float* __restrict__ Wo,
    const float* __restrict__ W1, const float* __restrict__ W2,
    const float* __restrict__ bq, const float* __restrict__ bk,
    const float* __restrict__ bv,
    short* __restrict__ WqkvT, short* __restrict__ WoT,
    short* __restrict__ W1T, short* __restrict__ W2T,
    float* __restrict__ bqkv, short* __restrict__ hb)
{
  const int id = blockIdx.x;
  const int t = threadIdx.x;

  if (id < 2560){
    // ---- weight transpose + bf16 cast: in[K][N] f32 -> out[N][K] bf16 ----
    __shared__ float tl[64][65];
    const float* src; short* dst; int K, N, tk, tn;
    if (id < 1280){
      int mat = id / 320, r = id % 320, lay = r / 64, tt = r % 64;
      tk = tt >> 3; tn = tt & 7; K = 512; N = 512;
      const float* s;
      short* d;
      if (mat == 0){ s = Wq; d = WqkvT + (size_t)lay * 851968; }
      else if (mat == 1){ s = Wk; d = WqkvT + (size_t)lay * 851968 + 262144; }
      else if (mat == 2){ s = Wv; d = WqkvT + (size_t)lay * 851968 + 524288; }
      else { s = Wo; d = WoT + (size_t)lay * 262144; }
      src = s + (size_t)lay * 262144; dst = d;
    } else if (id < 1920){
      int r = id - 1280, lay = r / 128, tt = r % 128;
      tk = tt >> 4; tn = tt & 15; K = 512; N = 1024;
      src = W1 + (size_t)lay * 524288; dst = W1T + (size_t)lay * 524288;
    } else {
      int r = id - 1920, lay = r / 128, tt = r % 128;
      tk = tt >> 3; tn = tt & 7; K = 1024; N = 512;
      src = W2 + (size_t)lay * 524288; dst = W2T + (size_t)lay * 524288;
    }
    const int k0 = tk * 64, n0 = tn * 64;
    const int lr = t >> 4, lc = (t & 15) * 4;
    #pragma unroll
    for (int s = 0; s < 4; s++){
      int row = lr + s * 16;
      float4 v = *(const float4*)&src[(size_t)(k0 + row) * N + n0 + lc];
      tl[row][lc + 0] = v.x; tl[row][lc + 1] = v.y;
      tl[row][lc + 2] = v.z; tl[row][lc + 3] = v.w;
    }
    __syncthreads();
    const int nr8 = t >> 3, kc8 = (t & 7) * 8;
    #pragma unroll
    for (int s = 0; s < 2; s++){
      int nr = nr8 + s * 32;
      bf16x8 o;
      #pragma unroll
      for (int e = 0; e < 8; e++) o[e] = f2bf(tl[kc8 + e][nr]);
      *(bf16x8*)&dst[(size_t)(n0 + nr) * K + k0 + kc8] = o;
    }
  } else if (id < 3200){
    // ---- Wrel rows 1536..1551 of WqkvT: WrelT[c][k] = Wq[k]·rel[c] ----
    const int bid = id - 2560;                     // 5 * 128
    const int lay = bid >> 7, kc = bid & 127;
    const int w = t >> 6, lane = t & 63;
    const int k = kc * 4 + w;
    const float* wrow = Wq + (size_t)lay * 262144 + (size_t)k * 512 + lane * 8;
    float qv[8];
    #pragma unroll
    for (int e = 0; e < 8; e++) qv[e] = wrow[e];
    short* dst = WqkvT + (size_t)lay * 851968;
    #pragma unroll
    for (int c = 0; c < 11; c++){
      const float* rp = rel + c * 512 + lane * 8;
      float s = 0.f;
      #pragma unroll
      for (int e = 0; e < 8; e++) s = fmaf(qv[e], rp[e], s);
      s = wsum(s);
      if (lane == 0) dst[(size_t)(1536 + c) * 512 + k] = f2bf(s);
    }
    if (lane == 0){
      #pragma unroll
      for (int c = 11; c < 16; c++) dst[(size_t)(1536 + c) * 512 + k] = 0;
    }
  } else if (id < 3233){
    // ---- bias concat + brel: bqkv[L][1664] ----
    int i = (id - 3200) * 256 + t;
    if (i < NL * 1664){
      int lay = i / 1664, c = i % 1664;
      float v;
      if      (c <  512) v = bq[lay * 512 + c];
      else if (c < 1024) v = bk[lay * 512 + c - 512];
      else if (c < 1536) v = bv[lay * 512 + c - 1024];
      else if (c < 1547){
        int cc = c - 1536;
        float s = 0.f;
        for (int j = 0; j < 512; j++) s += bq[lay * 512 + j] * rel[cc * 512 + j];
        v = s;
      } else v = 0.f;
      bqkv[i] = v;
    }
  } else {
    // ---- embedding gather (bf16 hb only) ----
    int idx = (id - 3233) * 256 + t;
    int row = idx >> 9;
    int d   = idx & 511;
    hb[idx] = f2bf(tok[x[row] * D + d]);
  }
}

// ---------------- staging: ROWS x (PAN*32) bf16 tile, panel-major LDS ----------------
template<int ROWS, int PAN>
__device__ __forceinline__ void stage_tile(const short* __restrict__ G, int ld,
                                           int kbase, char* ldsBase, int w, int l){
  constexpr int CALLS = ROWS * PAN / 64;   // per-wave gload16 calls
  #pragma unroll
  for (int c = 0; c < CALLS; c++){
    const int idx = w * CALLS + c;
    const int panel = idx / (ROWS / 16);
    const int chunk = idx % (ROWS / 16);
    const short* src = G + (size_t)(chunk * 16 + (l >> 2)) * ld
                         + kbase + panel * 32 + (l & 3) * 8;
    gload16(src, ldsBase + idx * 1024);
  }
}

// ---------------- generic MFMA NT GEMM, BMxBN tile, BK in {32,64} ------------------
// DEPTH-buffered with counted vmcnt (verified two-barrier skeleton from r11).
// DEPTH=3 only where the occupancy audit is clean (uniform grids, LDS fits):
//   QKV (48KB, 3/CU), FFN1 (48KB, 3/CU), O-proj & FFN2 (72KB, 2/CU = grid).
// Scores/PV stay DEPTH=2 (early-exit/variable-nk -> want small LDS, 3+ resident).
// MODE: 1 bf16+bias, 2 bf16+bias+relu, 3 scores->exp->bf16 p, 4 PV+normalize,
//       5 QKV fused (qkv | vT | qrel)
template<int BM, int BN, int MODE, int BK, int DEPTH>
__global__ __launch_bounds__(256) void mm_nt(
    const short* __restrict__ A, int ldA,
    const short* __restrict__ B, int ldB,
    const float* __restrict__ bias, void* __restrict__ C, int ldC,
    const float* __restrict__ qrel, short* __restrict__ vT,
    float* __restrict__ qrelOut,
    int K, long batA, long batB, long batC)
{
  constexpr int PAN = BK / 32;
  constexpr int CT  = (BM + BN) * PAN / 64;           // per-wave stage calls per tile
  constexpr int STAGE_SH = DEPTH * BK * (BM + BN);
  constexpr int BOUNCE_SH = BM * BN;
  constexpr int TB_ST = BM + 8;                       // padded transposed stride
  constexpr int TBOUNCE_SH = (MODE == 5) ? BN * TB_ST : 0;
  constexpr int SMEM_A = STAGE_SH > BOUNCE_SH ? STAGE_SH : BOUNCE_SH;
  constexpr int SMEM_SH = SMEM_A > TBOUNCE_SH ? SMEM_A : TBOUNCE_SH;
  __shared__ short smem[SMEM_SH];
  short* As = smem;                                   // DEPTH x BM*BK
  short* Bs = smem + DEPTH * BM * BK;                 // DEPTH x BN*BK

  // XCD-aware bijective swizzle (all launched grids have nwg % 8 == 0)
  const int gx = gridDim.x, gy = gridDim.y;
  int flat = ((int)blockIdx.z * gy + (int)blockIdx.y) * gx + (int)blockIdx.x;
  const int nwg = gx * gy * (int)gridDim.z;
  const int chunk = nwg >> 3;
  flat = (flat & 7) * chunk + (flat >> 3);
  const int bx = flat % gx;
  const int byy = (flat / gx) % gy;
  const int b = flat / (gx * gy);

  const int m0 = byy * BM, n0 = bx * BN;
  if (MODE == 3 && n0 >= m0 + BM) return;    // tile fully above causal diagonal
  int nk = K / BK;
  if (MODE == 4){ int km = (m0 + BM) / BK; nk = km < nk ? km : nk; }

  constexpr int FM = BM / 32, FN = BN / 32;
  f32x4 acc[FM][FN];
  const f32x4 z = {0.f, 0.f, 0.f, 0.f};
  #pragma unroll
  for (int m = 0; m < FM; m++)
    #pragma unroll
    for (int n = 0; n < FN; n++) acc[m][n] = z;

  const int t = threadIdx.x, l = t & 63, w = t >> 6;
  const short* Ag = A + (size_t)b * batA + (size_t)m0 * ldA;
  const short* Bg = B + (size_t)b * batB + (size_t)n0 * ldB;

  // prologue: issue tiles 0..DEPTH-2 (no drain)
  #pragma unroll
  for (int pv = 0; pv < DEPTH - 1; pv++){
    if (pv < nk){
      stage_tile<BM, PAN>(Ag, ldA, pv * BK, (char*)As + pv * (BM * BK * 2), w, l);
      stage_tile<BN, PAN>(Bg, ldB, pv * BK, (char*)Bs + pv * (BN * BK * 2), w, l);
    }
  }

  const int wm = (w >> 1) * (BM / 2), wn = (w & 1) * (BN / 2);
  const int kc = (l >> 4) * 8;
  float rs[FM];
  #pragma unroll
  for (int m = 0; m < FM; m++) rs[m] = 0.f;

  int cur = 0;
  for (int ks = 0; ks < nk; ks++){
    if (ks + DEPTH - 1 < nk){
      int nx = cur + DEPTH - 1; if (nx >= DEPTH) nx -= DEPTH;
      stage_tile<BM, PAN>(Ag, ldA, (ks + DEPTH - 1) * BK,
                          (char*)As + nx * (BM * BK * 2), w, l);
      stage_tile<BN, PAN>(Bg, ldB, (ks + DEPTH - 1) * BK,
                          (char*)Bs + nx * (BN * BK * 2), w, l);
      waitcnt_vm<(DEPTH - 1) * CT>();   // tile ks landed; newer tiles in flight
    } else if (ks + 1 < nk){
      waitcnt_vm<CT>();                 // one tile still in flight
    } else {
      waitcnt_vm<0>();
    }
    __builtin_amdgcn_s_barrier();       // tile ks visible to all waves
    asm volatile("" ::: "memory");
    const short* Ab = As + cur * (BM * BK);
    const short* Bb = Bs + cur * (BN * BK);
    #pragma unroll
    for (int p = 0; p < PAN; p++){
      bf16x8 af[FM], bfr[FN];
      #pragma unroll
      for (int m = 0; m < FM; m++)
        af[m] = *(const bf16x8*)&Ab[p * BM * 32 + (wm + m * 16 + (l & 15)) * 32 + kc];
      #pragma unroll
      for (int n = 0; n < FN; n++)
        bfr[n] = *(const bf16x8*)&Bb[p * BN * 32 + (wn + n * 16 + (l & 15)) * 32 + kc];
      if (MODE == 4){
        #pragma unroll
        for (int m = 0; m < FM; m++){
          float s = 0.f;
          #pragma unroll
          for (int e = 0; e < 8; e++) s += bf2f(af[m][e]);
          rs[m] += s;
        }
      }
      #pragma unroll
      for (int m = 0; m < FM; m++)
        #pragma unroll
        for (int n = 0; n < FN; n++)
          acc[m][n] = __builtin_amdgcn_mfma_f32_16x16x32_bf16(af[m], bfr[n], acc[m][n], 0, 0, 0);
    }
    asm volatile("" ::: "memory");
    __builtin_amdgcn_s_barrier();       // all waves done reading cur -> safe to overwrite
    cur = (cur == DEPTH - 1) ? 0 : cur + 1;
  }

  float invr[FM][4];
  if (MODE == 4){
    #pragma unroll
    for (int m = 0; m < FM; m++){
      float r = rs[m];
      r += __shfl_xor(r, 16, 64);
      r += __shfl_xor(r, 32, 64);
      #pragma unroll
      for (int rr = 0; rr < 4; rr++)
        invr[m][rr] = 1.0f / __shfl(r, (l >> 4) * 4 + rr, 64);
    }
  }

  const size_t cbase = (size_t)b * batC;

  if (MODE == 5 && n0 >= 1024){
    if (n0 < 1536){
      // V^T tiles via transposed LDS bounce: smem_t[d_local][s_local], padded.
      short* tb = smem;
      #pragma unroll
      for (int m = 0; m < FM; m++){
        const int rb = wm + m * 16 + (l >> 4) * 4;        // s_local base (mult of 4)
        #pragma unroll
        for (int n = 0; n < FN; n++){
          const int cl = wn + n * 16 + (l & 15);          // d_local
          const int col = n0 + cl;
          union { short s[4]; uint2 u; } tmp;
          #pragma unroll
          for (int r = 0; r < 4; r++) tmp.s[r] = f2bf(acc[m][n][r] + bias[col]);
          *(uint2*)&tb[cl * TB_ST + rb] = tmp.u;
        }
      }
      __syncthreads();
      const int dbase = n0 - 1024;
      constexpr int ITER_T = BM * BN / 2048;
      #pragma unroll
      for (int c = 0; c < ITER_T; c++){
        const int idx = c * 2048 + t * 8;
        const int dl = idx / BM, sl = idx % BM;
        const int grow = m0 + sl;
        const int bb = grow >> 9, s0 = grow & 511;
        *(bf16x8*)&vT[(size_t)bb * 262144 + (size_t)(dbase + dl) * 512 + s0] =
            *(const bf16x8*)&tb[dl * TB_ST + sl];
      }
      return;
    } else {
      // qrel tile: cols 1536..1551 used
      #pragma unroll
      for (int m = 0; m < FM; m++){
        const int rbase = m0 + wm + m * 16 + (l >> 4) * 4;
        #pragma unroll
        for (int n = 0; n < FN; n++){
          const int col = n0 + wn + n * 16 + (l & 15);
          if (col < 1552){
            const int c = col - 1536;
            #pragma unroll
            for (int r = 0; r < 4; r++)
              qrelOut[(size_t)(rbase + r) * 16 + c] = acc[m][n][r] + bias[col];
          }
        }
      }
      return;
    }
  }

  // ---- LDS-bounce epilogue (safe: all waves passed the loop's final barrier) ----
  #pragma unroll
  for (int m = 0; m < FM; m++){
    const int rb = wm + m * 16 + (l >> 4) * 4;
    #pragma unroll
    for (int n = 0; n < FN; n++){
      const int cl = wn + n * 16 + (l & 15);
      const int col = n0 + cl;
      #pragma unroll
      for (int r = 0; r < 4; r++){
        const int row = m0 + rb + r;
        float v = acc[m][n][r];
        short ov;
        if (MODE == 3){
          if (col <= row){
            int dd = row - col; if (dd > 10) dd = 10;
            float sv = v * (1.0f / 512.0f)
                     + qrel[((size_t)b * S + row) * 16 + dd] * 0.044194173824159216f;
            ov = f2bf(__expf(sv));
          } else ov = 0;
        } else if (MODE == 4){
          ov = f2bf(v * invr[m][r]);
        } else {
          v += bias[col];
          if (MODE == 2) v = fmaxf(v, 0.f);
          ov = f2bf(v);
        }
        smem[(rb + r) * BN + cl] = ov;
      }
    }
  }
  __syncthreads();
  constexpr int ITER = BM * BN / 2048;
  #pragma unroll
  for (int c = 0; c < ITER; c++){
    const int idx = c * 2048 + t * 8;
    const int row = idx / BN, cc = idx % BN;
    *(bf16x8*)&((short*)C)[cbase + (size_t)(m0 + row) * ldC + n0 + cc] =
        *(const bf16x8*)&smem[idx];
  }
}

// ---------------- h = LN(h + y): one wave per row, no barriers ----------------
template<int FINAL>
__global__ __launch_bounds__(256) void add_ln_k(
    short* __restrict__ hb, const short* __restrict__ y,
    const float* __restrict__ g, const float* __restrict__ be,
    float* __restrict__ hOut)
{
  const int t = threadIdx.x, w = t >> 6, l = t & 63;
  const int row = blockIdx.x * 4 + w;
  short* hbr = hb + (size_t)row * D;
  const short* yr = y + (size_t)row * D;
  bf16x8 h8 = *(const bf16x8*)&hbr[l * 8];
  bf16x8 y8 = *(const bf16x8*)&yr[l * 8];
  float v[8], s1 = 0.f, s2 = 0.f;
  #pragma unroll
  for (int e = 0; e < 8; e++){
    v[e] = bf2f(h8[e]) + bf2f(y8[e]);
    s1 += v[e];
    s2 += v[e] * v[e];
  }
  #pragma unroll
  for (int o = 32; o; o >>= 1){
    s1 += __shfl_xor(s1, o, 64);
    s2 += __shfl_xor(s2, o, 64);
  }
  const float mu  = s1 * (1.0f / 512.0f);
  const float var = s2 * (1.0f / 512.0f) - mu * mu;
  const float rcp = rsqrtf(var + 1e-5f);
  float4 g0 = *(const float4*)&g[l * 8];
  float4 g1 = *(const float4*)&g[l * 8 + 4];
  float4 b0 = *(const float4*)&be[l * 8];
  float4 b1 = *(const float4*)&be[l * 8 + 4];
  float gv[8] = {g0.x, g0.y, g0.z, g0.w, g1.x, g1.y, g1.z, g1.w};
  float bv[8] = {b0.x, b0.y, b0.z, b0.w, b1.x, b1.y, b1.z, b1.w};
  float o[8];
  #pragma unroll
  for (int e = 0; e < 8; e++) o[e] = (v[e] - mu) * rcp * gv[e] + bv[e];
  if (FINAL){
    float* ho = hOut + (size_t)row * D + l * 8;
    *(float4*)&ho[0] = make_float4(o[0], o[1], o[2], o[3]);
    *(float4*)&ho[4] = make_float4(o[4], o[5], o[6], o[7]);
  } else {
    bf16x8 ob;
    #pragma unroll
    for (int e = 0; e < 8; e++) ob[e] = f2bf(o[e]);
    *(bf16x8*)&hbr[l * 8] = ob;
  }
}

// ---------------- driver ----------------
extern "C" void kernel_launch(void* const* d_in, const int* in_sizes, int n_in,
                              void* d_out, int out_size, void* d_ws, size_t ws_size,
                              hipStream_t stream)
{
  const int*   x   = (const int*)  d_in[0];
  const float* tok = (const float*)d_in[1];
  const float* rel = (const float*)d_in[2];
  const float* Wq  = (const float*)d_in[3];  const float* bq = (const float*)d_in[4];
  const float* Wk  = (const float*)d_in[5];  const float* bk = (const float*)d_in[6];
  const float* Wv  = (const float*)d_in[7];  const float* bv = (const float*)d_in[8];
  const float* Wo  = (const float*)d_in[9];  const float* bo = (const float*)d_in[10];
  const float* W1  = (const float*)d_in[11]; const float* b1 = (const float*)d_in[12];
  const float* W2  = (const float*)d_in[13]; const float* b2 = (const float*)d_in[14];
  const float* g1  = (const float*)d_in[15]; const float* be1 = (const float*)d_in[16];
  const float* g2  = (const float*)d_in[17]; const float* be2 = (const float*)d_in[18];
  (void)in_sizes; (void)n_in; (void)out_size; (void)ws_size;

  float* h = (float*)d_out;                  // final f32 output only

  char* ws = (char*)d_ws;
  const size_t MB = 1 << 20;
  short* hb     = (short*)(ws);              // 8MB  bf16 residual stream
  short* qkv    = (short*)(ws + 8 * MB);     // 16MB [M][1024] (q|k)
  short* vT     = (short*)(ws + 24 * MB);    // 8MB  [b][D][S]
  short* p      = (short*)(ws + 32 * MB);    // 8MB  unnormalized exp scores
  short* ctx    = (short*)(ws + 40 * MB);    // 8MB
  short* xatt   = (short*)(ws + 48 * MB);    // 8MB (also ffout)
  short* ffmid  = (short*)(ws + 32 * MB);    // 16MB spans p+ctx (dead by FFN1)
  float* qrelb  = (float*)(ws + 56 * MB);    // 512KB [M][16] f32
  float* bqkv   = (float*)(ws + 56 * MB + 512 * 1024);  // L*1664*4 = 33KB
  short* wb     = (short*)(ws + 57 * MB);
  short* WqkvT  = wb;                                   // L*1664*512 bf16
  short* WoT    = WqkvT + (size_t)5 * 851968;           // L*512*512
  short* W1T    = WoT   + (size_t)5 * 262144;           // L*512*1024
  short* W2T    = W1T   + (size_t)5 * 524288;           // L*1024*512
  short* ffout  = xatt;

  const int M = NB * S;                      // 8192

  // fused preamble: wtrans | wrel | bcat | embed
  setup_k<<<19617, 256, 0, stream>>>(x, tok, rel, Wq, Wk, Wv, Wo, W1, W2,
                                     bq, bk, bv, WqkvT, WoT, W1T, W2T, bqkv, hb);

  for (int l = 0; l < NL; l++){
    // fused QKV+qrel: DEPTH=3 (48KB -> 3 blocks/CU, grid 3.25/CU)
    mm_nt<128, 128, 5, 32, 3><<<dim3(13, 64, 1), 256, 0, stream>>>(
        hb, 512, WqkvT + (size_t)l * 851968, 512, bqkv + l * 1664,
        qkv, 1024, nullptr, vT, qrelb, 512, 0, 0, 0);

    // scores -> exp -> p (unnormalized, zeros above diagonal), 64x128, DEPTH=2
    mm_nt<64, 128, 3, 64, 2><<<dim3(4, 8, NB), 256, 0, stream>>>(
        qkv, 1024, qkv + 512, 1024, nullptr,
        p, 512, qrelb, nullptr, nullptr, 512,
        (long)S * 1024, (long)S * 1024, (long)S * S);

    // PV + row-sum normalize, 64x128, K clipped, DEPTH=2
    mm_nt<64, 128, 4, 64, 2><<<dim3(4, 8, NB), 256, 0, stream>>>(
        p, 512, vT, 512, nullptr,
        ctx, 512, nullptr, nullptr, nullptr, 512,
        (long)S * S, (long)D * S, (long)S * D);

    // O-proj: DEPTH=3 (72KB -> 2 blocks/CU = grid residency)
    mm_nt<128, 64, 1, 64, 3><<<dim3(8, 64, 1), 256, 0, stream>>>(
        ctx, 512, WoT + (size_t)l * 262144, 512, bo + l * 512,
        xatt, 512, nullptr, nullptr, nullptr, 512, 0, 0, 0);
    add_ln_k<0><<<M / 4, 256, 0, stream>>>(hb, xatt, g1 + l * 512, be1 + l * 512, nullptr);

    // FFN1: DEPTH=3 (48KB -> 3 blocks/CU)
    mm_nt<128, 128, 2, 32, 3><<<dim3(8, 64, 1), 256, 0, stream>>>(
        hb, 512, W1T + (size_t)l * 524288, 512, b1 + l * 1024,
        ffmid, 1024, nullptr, nullptr, nullptr, 512, 0, 0, 0);
    // FFN2: DEPTH=3 (72KB -> 2 blocks/CU = grid residency)
    mm_nt<128, 64, 1, 64, 3><<<dim3(8, 64, 1), 256, 0, stream>>>(
        ffmid, 1024, W2T + (size_t)l * 524288, 1024, b2 + l * 512,
        ffout, 512, nullptr, nullptr, nullptr, 1024, 0, 0, 0);
    if (l < NL - 1)
      add_ln_k<0><<<M / 4, 256, 0, stream>>>(hb, ffout, g2 + l * 512, be2 + l * 512, nullptr);
    else
      add_ln_k<1><<<M / 4, 256, 0, stream>>>(hb, ffout, g2 + l * 512, be2 + l * 512, h);
  }
}

// Round 15
// 521.404 us; speedup vs baseline: 1.0209x; 1.0209x over previous
//
#include <hip/hip_runtime.h>
#include <math.h>

#define S 512
#define D 512
#define FFD 1024
#define NB 16
#define NL 5

typedef __attribute__((ext_vector_type(8))) short bf16x8;
typedef __attribute__((ext_vector_type(4))) float f32x4;

// ---------------- bf16 helpers ----------------
__device__ __forceinline__ short f2bf(float f){
  union { float f; unsigned u; } c; c.f = f;
  unsigned r = c.u + 0x7FFFu + ((c.u >> 16) & 1u);   // RNE
  return (short)(r >> 16);
}
__device__ __forceinline__ float bf2f(short s){
  union { unsigned u; float f; } c; c.u = ((unsigned)(unsigned short)s) << 16;
  return c.f;
}

// async global->LDS, 16B per lane; lds ptr must be wave-uniform base
__device__ __forceinline__ void gload16(const void* g, void* l){
  __builtin_amdgcn_global_load_lds(
      (const __attribute__((address_space(1))) void*)g,
      (__attribute__((address_space(3))) void*)l, 16, 0, 0);
}

// counted vmcnt wait (T4): wait until at most N of this wave's loads in flight
template<int N>
__device__ __forceinline__ void waitcnt_vm(){
  if      constexpr (N == 0)  asm volatile("s_waitcnt vmcnt(0)"  ::: "memory");
  else if constexpr (N == 2)  asm volatile("s_waitcnt vmcnt(2)"  ::: "memory");
  else if constexpr (N == 4)  asm volatile("s_waitcnt vmcnt(4)"  ::: "memory");
  else if constexpr (N == 6)  asm volatile("s_waitcnt vmcnt(6)"  ::: "memory");
  else if constexpr (N == 8)  asm volatile("s_waitcnt vmcnt(8)"  ::: "memory");
  else if constexpr (N == 10) asm volatile("s_waitcnt vmcnt(10)" ::: "memory");
  else                        asm volatile("s_waitcnt vmcnt(12)" ::: "memory");
}

// ---------------- reduction helpers ----------------
__device__ __forceinline__ float wsum(float v){
  #pragma unroll
  for (int o = 32; o; o >>= 1) v += __shfl_down(v, o, 64);
  return v;
}

// ---------------- fused setup: wtrans | wrel | bcat | embed ----------------
// block-id ranges: [0,2560) wtrans, [2560,3200) wrel, [3200,3233) bcat,
//                  [3233,19617) embed. All branches write disjoint buffers.
__global__ __launch_bounds__(256) void setup_k(
    const int* __restrict__ x, const float* __restrict__ tok,
    const float* __restrict__ rel,
    const float* __restrict__ Wq, const float* __restrict__ Wk,
    const float* __restrict__ Wv, const float* __restrict__ Wo,
    const float* __restrict__ W1, const float* __restrict__ W2,
    const float* __restrict__ bq, const float* __restrict__ bk,
    const float* __restrict__ bv,
    short* __restrict__ WqkvT, short* __restrict__ WoT,
    short* __restrict__ W1T, short* __restrict__ W2T,
    float* __restrict__ bqkv, short* __restrict__ hb)
{
  const int id = blockIdx.x;
  const int t = threadIdx.x;

  if (id < 2560){
    // ---- weight transpose + bf16 cast: in[K][N] f32 -> out[N][K] bf16 ----
    __shared__ float tl[64][65];
    const float* src; short* dst; int K, N, tk, tn;
    if (id < 1280){
      int mat = id / 320, r = id % 320, lay = r / 64, tt = r % 64;
      tk = tt >> 3; tn = tt & 7; K = 512; N = 512;
      const float* s;
      short* d;
      if (mat == 0){ s = Wq; d = WqkvT + (size_t)lay * 851968; }
      else if (mat == 1){ s = Wk; d = WqkvT + (size_t)lay * 851968 + 262144; }
      else if (mat == 2){ s = Wv; d = WqkvT + (size_t)lay * 851968 + 524288; }
      else { s = Wo; d = WoT + (size_t)lay * 262144; }
      src = s + (size_t)lay * 262144; dst = d;
    } else if (id < 1920){
      int r = id - 1280, lay = r / 128, tt = r % 128;
      tk = tt >> 4; tn = tt & 15; K = 512; N = 1024;
      src = W1 + (size_t)lay * 524288; dst = W1T + (size_t)lay * 524288;
    } else {
      int r = id - 1920, lay = r / 128, tt = r % 128;
      tk = tt >> 3; tn = tt & 7; K = 1024; N = 512;
      src = W2 + (size_t)lay * 524288; dst = W2T + (size_t)lay * 524288;
    }
    const int k0 = tk * 64, n0 = tn * 64;
    const int lr = t >> 4, lc = (t & 15) * 4;
    #pragma unroll
    for (int s = 0; s < 4; s++){
      int row = lr + s * 16;
      float4 v = *(const float4*)&src[(size_t)(k0 + row) * N + n0 + lc];
      tl[row][lc + 0] = v.x; tl[row][lc + 1] = v.y;
      tl[row][lc + 2] = v.z; tl[row][lc + 3] = v.w;
    }
    __syncthreads();
    const int nr8 = t >> 3, kc8 = (t & 7) * 8;
    #pragma unroll
    for (int s = 0; s < 2; s++){
      int nr = nr8 + s * 32;
      bf16x8 o;
      #pragma unroll
      for (int e = 0; e < 8; e++) o[e] = f2bf(tl[kc8 + e][nr]);
      *(bf16x8*)&dst[(size_t)(n0 + nr) * K + k0 + kc8] = o;
    }
  } else if (id < 3200){
    // ---- Wrel rows 1536..1551 of WqkvT: WrelT[c][k] = Wq[k]·rel[c] ----
    const int bid = id - 2560;                     // 5 * 128
    const int lay = bid >> 7, kc = bid & 127;
    const int w = t >> 6, lane = t & 63;
    const int k = kc * 4 + w;
    const float* wrow = Wq + (size_t)lay * 262144 + (size_t)k * 512 + lane * 8;
    float qv[8];
    #pragma unroll
    for (int e = 0; e < 8; e++) qv[e] = wrow[e];
    short* dst = WqkvT + (size_t)lay * 851968;
    #pragma unroll
    for (int c = 0; c < 11; c++){
      const float* rp = rel + c * 512 + lane * 8;
      float s = 0.f;
      #pragma unroll
      for (int e = 0; e < 8; e++) s = fmaf(qv[e], rp[e], s);
      s = wsum(s);
      if (lane == 0) dst[(size_t)(1536 + c) * 512 + k] = f2bf(s);
    }
    if (lane == 0){
      #pragma unroll
      for (int c = 11; c < 16; c++) dst[(size_t)(1536 + c) * 512 + k] = 0;
    }
  } else if (id < 3233){
    // ---- bias concat + brel: bqkv[L][1664] ----
    int i = (id - 3200) * 256 + t;
    if (i < NL * 1664){
      int lay = i / 1664, c = i % 1664;
      float v;
      if      (c <  512) v = bq[lay * 512 + c];
      else if (c < 1024) v = bk[lay * 512 + c - 512];
      else if (c < 1536) v = bv[lay * 512 + c - 1024];
      else if (c < 1547){
        int cc = c - 1536;
        float s = 0.f;
        for (int j = 0; j < 512; j++) s += bq[lay * 512 + j] * rel[cc * 512 + j];
        v = s;
      } else v = 0.f;
      bqkv[i] = v;
    }
  } else {
    // ---- embedding gather (bf16 hb only) ----
    int idx = (id - 3233) * 256 + t;
    int row = idx >> 9;
    int d   = idx & 511;
    hb[idx] = f2bf(tok[x[row] * D + d]);
  }
}

// ---------------- staging: ROWS x (PAN*32) bf16 tile, panel-major LDS ----------------
template<int ROWS, int PAN>
__device__ __forceinline__ void stage_tile(const short* __restrict__ G, int ld,
                                           int kbase, char* ldsBase, int w, int l){
  constexpr int CALLS = ROWS * PAN / 64;   // per-wave gload16 calls
  #pragma unroll
  for (int c = 0; c < CALLS; c++){
    const int idx = w * CALLS + c;
    const int panel = idx / (ROWS / 16);
    const int chunk = idx % (ROWS / 16);
    const short* src = G + (size_t)(chunk * 16 + (l >> 2)) * ld
                         + kbase + panel * 32 + (l & 3) * 8;
    gload16(src, ldsBase + idx * 1024);
  }
}

// ---------------- generic MFMA NT GEMM, BMxBN tile, BK in {32,64} ------------------
// DEPTH-buffered with counted vmcnt (verified two-barrier skeleton from r11).
// r13-champion depths: DEPTH=3 ONLY for FFN1 (48KB, 3 blocks/CU capacity vs 2/CU
// grid); all other GEMMs DEPTH=2 (r14 showed QKV/O/FFN2 at DEPTH=3 regress).
// MODE: 1 bf16+bias, 2 bf16+bias+relu, 3 scores->exp->bf16 p, 4 PV+normalize,
//       5 QKV fused (qkv | vT | qrel)
template<int BM, int BN, int MODE, int BK, int DEPTH>
__global__ __launch_bounds__(256) void mm_nt(
    const short* __restrict__ A, int ldA,
    const short* __restrict__ B, int ldB,
    const float* __restrict__ bias, void* __restrict__ C, int ldC,
    const float* __restrict__ qrel, short* __restrict__ vT,
    float* __restrict__ qrelOut,
    int K, long batA, long batB, long batC)
{
  constexpr int PAN = BK / 32;
  constexpr int CT  = (BM + BN) * PAN / 64;           // per-wave stage calls per tile
  constexpr int STAGE_SH = DEPTH * BK * (BM + BN);
  constexpr int BOUNCE_SH = BM * BN;
  constexpr int TB_ST = BM + 8;                       // padded transposed stride
  constexpr int TBOUNCE_SH = (MODE == 5) ? BN * TB_ST : 0;
  constexpr int SMEM_A = STAGE_SH > BOUNCE_SH ? STAGE_SH : BOUNCE_SH;
  constexpr int SMEM_SH = SMEM_A > TBOUNCE_SH ? SMEM_A : TBOUNCE_SH;
  __shared__ short smem[SMEM_SH];
  short* As = smem;                                   // DEPTH x BM*BK
  short* Bs = smem + DEPTH * BM * BK;                 // DEPTH x BN*BK

  // XCD-aware bijective swizzle (all launched grids have nwg % 8 == 0)
  const int gx = gridDim.x, gy = gridDim.y;
  int flat = ((int)blockIdx.z * gy + (int)blockIdx.y) * gx + (int)blockIdx.x;
  const int nwg = gx * gy * (int)gridDim.z;
  const int chunk = nwg >> 3;
  flat = (flat & 7) * chunk + (flat >> 3);
  const int bx = flat % gx;
  const int byy = (flat / gx) % gy;
  const int b = flat / (gx * gy);

  const int m0 = byy * BM, n0 = bx * BN;
  if (MODE == 3 && n0 >= m0 + BM) return;    // tile fully above causal diagonal
  int nk = K / BK;
  if (MODE == 4){ int km = (m0 + BM) / BK; nk = km < nk ? km : nk; }

  constexpr int FM = BM / 32, FN = BN / 32;
  f32x4 acc[FM][FN];
  const f32x4 z = {0.f, 0.f, 0.f, 0.f};
  #pragma unroll
  for (int m = 0; m < FM; m++)
    #pragma unroll
    for (int n = 0; n < FN; n++) acc[m][n] = z;

  const int t = threadIdx.x, l = t & 63, w = t >> 6;
  const short* Ag = A + (size_t)b * batA + (size_t)m0 * ldA;
  const short* Bg = B + (size_t)b * batB + (size_t)n0 * ldB;

  // prologue: issue tiles 0..DEPTH-2 (no drain)
  #pragma unroll
  for (int pv = 0; pv < DEPTH - 1; pv++){
    if (pv < nk){
      stage_tile<BM, PAN>(Ag, ldA, pv * BK, (char*)As + pv * (BM * BK * 2), w, l);
      stage_tile<BN, PAN>(Bg, ldB, pv * BK, (char*)Bs + pv * (BN * BK * 2), w, l);
    }
  }

  const int wm = (w >> 1) * (BM / 2), wn = (w & 1) * (BN / 2);
  const int kc = (l >> 4) * 8;
  float rs[FM];
  #pragma unroll
  for (int m = 0; m < FM; m++) rs[m] = 0.f;

  int cur = 0;
  for (int ks = 0; ks < nk; ks++){
    if (ks + DEPTH - 1 < nk){
      int nx = cur + DEPTH - 1; if (nx >= DEPTH) nx -= DEPTH;
      stage_tile<BM, PAN>(Ag, ldA, (ks + DEPTH - 1) * BK,
                          (char*)As + nx * (BM * BK * 2), w, l);
      stage_tile<BN, PAN>(Bg, ldB, (ks + DEPTH - 1) * BK,
                          (char*)Bs + nx * (BN * BK * 2), w, l);
      waitcnt_vm<(DEPTH - 1) * CT>();   // tile ks landed; newer tiles in flight
    } else if (ks + 1 < nk){
      waitcnt_vm<CT>();                 // one tile still in flight
    } else {
      waitcnt_vm<0>();
    }
    __builtin_amdgcn_s_barrier();       // tile ks visible to all waves
    asm volatile("" ::: "memory");
    const short* Ab = As + cur * (BM * BK);
    const short* Bb = Bs + cur * (BN * BK);
    #pragma unroll
    for (int p = 0; p < PAN; p++){
      bf16x8 af[FM], bfr[FN];
      #pragma unroll
      for (int m = 0; m < FM; m++)
        af[m] = *(const bf16x8*)&Ab[p * BM * 32 + (wm + m * 16 + (l & 15)) * 32 + kc];
      #pragma unroll
      for (int n = 0; n < FN; n++)
        bfr[n] = *(const bf16x8*)&Bb[p * BN * 32 + (wn + n * 16 + (l & 15)) * 32 + kc];
      if (MODE == 4){
        #pragma unroll
        for (int m = 0; m < FM; m++){
          float s = 0.f;
          #pragma unroll
          for (int e = 0; e < 8; e++) s += bf2f(af[m][e]);
          rs[m] += s;
        }
      }
      #pragma unroll
      for (int m = 0; m < FM; m++)
        #pragma unroll
        for (int n = 0; n < FN; n++)
          acc[m][n] = __builtin_amdgcn_mfma_f32_16x16x32_bf16(af[m], bfr[n], acc[m][n], 0, 0, 0);
    }
    asm volatile("" ::: "memory");
    __builtin_amdgcn_s_barrier();       // all waves done reading cur -> safe to overwrite
    cur = (cur == DEPTH - 1) ? 0 : cur + 1;
  }

  float invr[FM][4];
  if (MODE == 4){
    #pragma unroll
    for (int m = 0; m < FM; m++){
      float r = rs[m];
      r += __shfl_xor(r, 16, 64);
      r += __shfl_xor(r, 32, 64);
      #pragma unroll
      for (int rr = 0; rr < 4; rr++)
        invr[m][rr] = 1.0f / __shfl(r, (l >> 4) * 4 + rr, 64);
    }
  }

  const size_t cbase = (size_t)b * batC;

  if (MODE == 5 && n0 >= 1024){
    if (n0 < 1536){
      // V^T tiles via transposed LDS bounce: smem_t[d_local][s_local], padded.
      short* tb = smem;
      #pragma unroll
      for (int m = 0; m < FM; m++){
        const int rb = wm + m * 16 + (l >> 4) * 4;        // s_local base (mult of 4)
        #pragma unroll
        for (int n = 0; n < FN; n++){
          const int cl = wn + n * 16 + (l & 15);          // d_local
          const int col = n0 + cl;
          union { short s[4]; uint2 u; } tmp;
          #pragma unroll
          for (int r = 0; r < 4; r++) tmp.s[r] = f2bf(acc[m][n][r] + bias[col]);
          *(uint2*)&tb[cl * TB_ST + rb] = tmp.u;
        }
      }
      __syncthreads();
      const int dbase = n0 - 1024;
      constexpr int ITER_T = BM * BN / 2048;
      #pragma unroll
      for (int c = 0; c < ITER_T; c++){
        const int idx = c * 2048 + t * 8;
        const int dl = idx / BM, sl = idx % BM;
        const int grow = m0 + sl;
        const int bb = grow >> 9, s0 = grow & 511;
        *(bf16x8*)&vT[(size_t)bb * 262144 + (size_t)(dbase + dl) * 512 + s0] =
            *(const bf16x8*)&tb[dl * TB_ST + sl];
      }
      return;
    } else {
      // qrel tile: cols 1536..1551 used
      #pragma unroll
      for (int m = 0; m < FM; m++){
        const int rbase = m0 + wm + m * 16 + (l >> 4) * 4;
        #pragma unroll
        for (int n = 0; n < FN; n++){
          const int col = n0 + wn + n * 16 + (l & 15);
          if (col < 1552){
            const int c = col - 1536;
            #pragma unroll
            for (int r = 0; r < 4; r++)
              qrelOut[(size_t)(rbase + r) * 16 + c] = acc[m][n][r] + bias[col];
          }
        }
      }
      return;
    }
  }

  // ---- LDS-bounce epilogue (safe: all waves passed the loop's final barrier) ----
  #pragma unroll
  for (int m = 0; m < FM; m++){
    const int rb = wm + m * 16 + (l >> 4) * 4;
    #pragma unroll
    for (int n = 0; n < FN; n++){
      const int cl = wn + n * 16 + (l & 15);
      const int col = n0 + cl;
      #pragma unroll
      for (int r = 0; r < 4; r++){
        const int row = m0 + rb + r;
        float v = acc[m][n][r];
        short ov;
        if (MODE == 3){
          if (col <= row){
            int dd = row - col; if (dd > 10) dd = 10;
            float sv = v * (1.0f / 512.0f)
                     + qrel[((size_t)b * S + row) * 16 + dd] * 0.044194173824159216f;
            ov = f2bf(__expf(sv));
          } else ov = 0;
        } else if (MODE == 4){
          ov = f2bf(v * invr[m][r]);
        } else {
          v += bias[col];
          if (MODE == 2) v = fmaxf(v, 0.f);
          ov = f2bf(v);
        }
        smem[(rb + r) * BN + cl] = ov;
      }
    }
  }
  __syncthreads();
  constexpr int ITER = BM * BN / 2048;
  #pragma unroll
  for (int c = 0; c < ITER; c++){
    const int idx = c * 2048 + t * 8;
    const int row = idx / BN, cc = idx % BN;
    *(bf16x8*)&((short*)C)[cbase + (size_t)(m0 + row) * ldC + n0 + cc] =
        *(const bf16x8*)&smem[idx];
  }
}

// ---------------- h = LN(h + y): one wave per row, no barriers ----------------
template<int FINAL>
__global__ __launch_bounds__(256) void add_ln_k(
    short* __restrict__ hb, const short* __restrict__ y,
    const float* __restrict__ g, const float* __restrict__ be,
    float* __restrict__ hOut)
{
  const int t = threadIdx.x, w = t >> 6, l = t & 63;
  const int row = blockIdx.x * 4 + w;
  short* hbr = hb + (size_t)row * D;
  const short* yr = y + (size_t)row * D;
  bf16x8 h8 = *(const bf16x8*)&hbr[l * 8];
  bf16x8 y8 = *(const bf16x8*)&yr[l * 8];
  float v[8], s1 = 0.f, s2 = 0.f;
  #pragma unroll
  for (int e = 0; e < 8; e++){
    v[e] = bf2f(h8[e]) + bf2f(y8[e]);
    s1 += v[e];
    s2 += v[e] * v[e];
  }
  #pragma unroll
  for (int o = 32; o; o >>= 1){
    s1 += __shfl_xor(s1, o, 64);
    s2 += __shfl_xor(s2, o, 64);
  }
  const float mu  = s1 * (1.0f / 512.0f);
  const float var = s2 * (1.0f / 512.0f) - mu * mu;
  const float rcp = rsqrtf(var + 1e-5f);
  float4 g0 = *(const float4*)&g[l * 8];
  float4 g1 = *(const float4*)&g[l * 8 + 4];
  float4 b0 = *(const float4*)&be[l * 8];
  float4 b1 = *(const float4*)&be[l * 8 + 4];
  float gv[8] = {g0.x, g0.y, g0.z, g0.w, g1.x, g1.y, g1.z, g1.w};
  float bv[8] = {b0.x, b0.y, b0.z, b0.w, b1.x, b1.y, b1.z, b1.w};
  float o[8];
  #pragma unroll
  for (int e = 0; e < 8; e++) o[e] = (v[e] - mu) * rcp * gv[e] + bv[e];
  if (FINAL){
    float* ho = hOut + (size_t)row * D + l * 8;
    *(float4*)&ho[0] = make_float4(o[0], o[1], o[2], o[3]);
    *(float4*)&ho[4] = make_float4(o[4], o[5], o[6], o[7]);
  } else {
    bf16x8 ob;
    #pragma unroll
    for (int e = 0; e < 8; e++) ob[e] = f2bf(o[e]);
    *(bf16x8*)&hbr[l * 8] = ob;
  }
}

// ---------------- driver ----------------
extern "C" void kernel_launch(void* const* d_in, const int* in_sizes, int n_in,
                              void* d_out, int out_size, void* d_ws, size_t ws_size,
                              hipStream_t stream)
{
  const int*   x   = (const int*)  d_in[0];
  const float* tok = (const float*)d_in[1];
  const float* rel = (const float*)d_in[2];
  const float* Wq  = (const float*)d_in[3];  const float* bq = (const float*)d_in[4];
  const float* Wk  = (const float*)d_in[5];  const float* bk = (const float*)d_in[6];
  const float* Wv  = (const float*)d_in[7];  const float* bv = (const float*)d_in[8];
  const float* Wo  = (const float*)d_in[9];  const float* bo = (const float*)d_in[10];
  const float* W1  = (const float*)d_in[11]; const float* b1 = (const float*)d_in[12];
  const float* W2  = (const float*)d_in[13]; const float* b2 = (const float*)d_in[14];
  const float* g1  = (const float*)d_in[15]; const float* be1 = (const float*)d_in[16];
  const float* g2  = (const float*)d_in[17]; const float* be2 = (const float*)d_in[18];
  (void)in_sizes; (void)n_in; (void)out_size; (void)ws_size;

  float* h = (float*)d_out;                  // final f32 output only

  char* ws = (char*)d_ws;
  const size_t MB = 1 << 20;
  short* hb     = (short*)(ws);              // 8MB  bf16 residual stream
  short* qkv    = (short*)(ws + 8 * MB);     // 16MB [M][1024] (q|k)
  short* vT     = (short*)(ws + 24 * MB);    // 8MB  [b][D][S]
  short* p      = (short*)(ws + 32 * MB);    // 8MB  unnormalized exp scores
  short* ctx    = (short*)(ws + 40 * MB);    // 8MB
  short* xatt   = (short*)(ws + 48 * MB);    // 8MB (also ffout)
  short* ffmid  = (short*)(ws + 32 * MB);    // 16MB spans p+ctx (dead by FFN1)
  float* qrelb  = (float*)(ws + 56 * MB);    // 512KB [M][16] f32
  float* bqkv   = (float*)(ws + 56 * MB + 512 * 1024);  // L*1664*4 = 33KB
  short* wb     = (short*)(ws + 57 * MB);
  short* WqkvT  = wb;                                   // L*1664*512 bf16
  short* WoT    = WqkvT + (size_t)5 * 851968;           // L*512*512
  short* W1T    = WoT   + (size_t)5 * 262144;           // L*512*1024
  short* W2T    = W1T   + (size_t)5 * 524288;           // L*1024*512
  short* ffout  = xatt;

  const int M = NB * S;                      // 8192

  // fused preamble: wtrans | wrel | bcat | embed
  setup_k<<<19617, 256, 0, stream>>>(x, tok, rel, Wq, Wk, Wv, Wo, W1, W2,
                                     bq, bk, bv, WqkvT, WoT, W1T, W2T, bqkv, hb);

  for (int l = 0; l < NL; l++){
    // fused QKV+qrel: DEPTH=2 (r13 champion config)
    mm_nt<128, 128, 5, 32, 2><<<dim3(13, 64, 1), 256, 0, stream>>>(
        hb, 512, WqkvT + (size_t)l * 851968, 512, bqkv + l * 1664,
        qkv, 1024, nullptr, vT, qrelb, 512, 0, 0, 0);

    // scores -> exp -> p (unnormalized, zeros above diagonal), 64x128, DEPTH=2
    mm_nt<64, 128, 3, 64, 2><<<dim3(4, 8, NB), 256, 0, stream>>>(
        qkv, 1024, qkv + 512, 1024, nullptr,
        p, 512, qrelb, nullptr, nullptr, 512,
        (long)S * 1024, (long)S * 1024, (long)S * S);

    // PV + row-sum normalize, 64x128, K clipped, DEPTH=2
    mm_nt<64, 128, 4, 64, 2><<<dim3(4, 8, NB), 256, 0, stream>>>(
        p, 512, vT, 512, nullptr,
        ctx, 512, nullptr, nullptr, nullptr, 512,
        (long)S * S, (long)D * S, (long)S * D);

    // O-proj: DEPTH=2 (r13 champion config)
    mm_nt<128, 64, 1, 64, 2><<<dim3(8, 64, 1), 256, 0, stream>>>(
        ctx, 512, WoT + (size_t)l * 262144, 512, bo + l * 512,
        xatt, 512, nullptr, nullptr, nullptr, 512, 0, 0, 0);
    add_ln_k<0><<<M / 4, 256, 0, stream>>>(hb, xatt, g1 + l * 512, be1 + l * 512, nullptr);

    // FFN1: DEPTH=3 (48KB LDS -> 3 blocks/CU capacity vs 2/CU grid -> free depth)
    mm_nt<128, 128, 2, 32, 3><<<dim3(8, 64, 1), 256, 0, stream>>>(
        hb, 512, W1T + (size_t)l * 524288, 512, b1 + l * 1024,
        ffmid, 1024, nullptr, nullptr, nullptr, 512, 0, 0, 0);
    // FFN2: DEPTH=2 (r13 champion config)
    mm_nt<128, 64, 1, 64, 2><<<dim3(8, 64, 1), 256, 0, stream>>>(
        ffmid, 1024, W2T + (size_t)l * 524288, 1024, b2 + l * 512,
        ffout, 512, nullptr, nullptr, nullptr, 1024, 0, 0, 0);
    if (l < NL - 1)
      add_ln_k<0><<<M / 4, 256, 0, stream>>>(hb, ffout, g2 + l * 512, be2 + l * 512, nullptr);
    else
      add_ln_k<1><<<M / 4, 256, 0, stream>>>(hb, ffout, g2 + l * 512, be2 + l * 512, h);
  }
}